// Round 10
// baseline (292.574 us; speedup 1.0000x reference)
//
#include <hip/hip_runtime.h>
#include <cstdint>
#include <cstddef>

#define N_ 2
#define B_ 2
#define D_ 512
#define HW_ 256
#define DK_ 64
#define DKC_ 128
#define G_ 4
#define NBLK_ 32

typedef float f4 __attribute__((ext_vector_type(4)));

// ---- workspace offsets (in floats) ----
constexpr size_t OFF_TSR = 0;                       // src tokens (reused as T3 partial kc=1)
constexpr size_t OFF_TSI = 524288;
constexpr size_t OFF_TTR = 1048576;
constexpr size_t OFF_TTI = 1572864;
constexpr size_t OFF_QSR = 2097152;                 // rel q (src) [(n*hw), b, 64]
constexpr size_t OFF_QSI = OFF_QSR + 65536;
constexpr size_t OFF_QTR = OFF_QSI + 65536;
constexpr size_t OFF_QTI = OFF_QTR + 65536;
constexpr size_t OFF_AS  = OFF_QTI + 65536;         // self-attn A (src) [nb,256,256]
constexpr size_t OFF_AT  = OFF_AS + 262144;
constexpr size_t OFF_YSR = OFF_AT + 262144;         // src + attn out (UNSCALED mem)
constexpr size_t OFF_YSI = OFF_YSR + 524288;
constexpr size_t OFF_YTR = OFF_YSI + 524288;        // tgt + attn out (UNSCALED x)
constexpr size_t OFF_YTI = OFF_YTR + 524288;
constexpr size_t OFF_QCR = OFF_YTI + 524288;        // cross q [l,b,128]
constexpr size_t OFF_QCI = OFF_QCR + 131072;
constexpr size_t OFF_KCR = OFF_QCI + 131072;
constexpr size_t OFF_KCI = OFF_KCR + 131072;
constexpr size_t OFF_AC  = OFF_KCI + 131072;        // cross scores -> A [b,512,512]
constexpr size_t OFF_T3R = OFF_AC + 524288;         // t3 partial kc=0 (then z)
constexpr size_t OFF_T3I = OFF_T3R + 524288;
constexpr size_t OFF_MR  = OFF_T3I + 524288;        // mask scalar [b,512]
constexpr size_t OFF_MI  = OFF_MR + 1024;
constexpr size_t OFF_P1  = OFF_MI + 1024;           // ss partials [16 groups][64 slots]
constexpr size_t OFF_P2  = OFF_P1 + 1024;           // [16][32]
constexpr size_t OFF_P3  = OFF_P2 + 512;            // [8][32]

// ---- reductions ----
template<int NT>
__device__ __forceinline__ float blk_sum(float v, float* sh) {
  int tid = threadIdx.x;
  sh[tid] = v; __syncthreads();
  #pragma unroll
  for (int s = NT/2; s > 0; s >>= 1) { if (tid < s) sh[tid] += sh[tid+s]; __syncthreads(); }
  float r = sh[0]; __syncthreads(); return r;
}
template<int NT>
__device__ __forceinline__ float blk_max(float v, float* sh) {
  int tid = threadIdx.x;
  sh[tid] = v; __syncthreads();
  #pragma unroll
  for (int s = NT/2; s > 0; s >>= 1) { if (tid < s) sh[tid] = fmaxf(sh[tid], sh[tid+s]); __syncthreads(); }
  float r = sh[0]; __syncthreads(); return r;
}
__device__ __forceinline__ float wave_sum32(float v) {
  #pragma unroll
  for (int o = 16; o; o >>= 1) v += __shfl_xor(v, o, 64);
  return v;
}
__device__ __forceinline__ float wave_sum64(float v) {
  #pragma unroll
  for (int o = 32; o; o >>= 1) v += __shfl_xor(v, o, 64);
  return v;
}
__device__ __forceinline__ float wave_max64(float v) {
  #pragma unroll
  for (int o = 32; o; o >>= 1) v = fmaxf(v, __shfl_xor(v, o, 64));
  return v;
}
__device__ __forceinline__ float scale_from(const float* part, int q) {
  float ss = 0.f;
  #pragma unroll
  for (int j = 0; j < NBLK_; ++j) ss += part[q*NBLK_ + j];
  return 4.f * rsqrtf(ss + 1e-5f);
}
__device__ __forceinline__ float scale_from64(const float* part, int q) {
  float ss = 0.f;
  #pragma unroll
  for (int j = 0; j < 64; ++j) ss += part[q*64 + j];
  return 4.f * rsqrtf(ss + 1e-5f);
}
// async global->LDS, 16B/lane; LDS dest = wave-uniform base + lane*16
__device__ __forceinline__ void gload16(const float* g, float* l) {
  __builtin_amdgcn_global_load_lds((const __attribute__((address_space(1))) void*)g,
                                   (__attribute__((address_space(3))) void*)l, 16, 0, 0);
}

// ---- 1: tokenize transpose ----
__global__ void k_transpose(const float* sR, const float* sI, const float* tR, const float* tI, float* ws) {
  int which = blockIdx.y;
  const float* in = (which==0)? sR : (which==1)? sI : (which==2)? tR : tI;
  float* out = ws + ((which==0)? OFF_TSR : (which==1)? OFF_TSI : (which==2)? OFF_TTR : OFF_TTI);
  int bx = blockIdx.x;
  int pt = bx & 3, dt = (bx>>2)&7, nb = bx>>5;
  int ni = nb>>1, bi = nb&1;
  __shared__ float tile[64][65];
  int tid = threadIdx.x;
  int p0 = pt*64, d0 = dt*64;
  #pragma unroll
  for (int it=0; it<16; ++it) {
    int i = it*256 + tid; int row = i>>6, col = i&63;
    tile[row][col] = in[(size_t)(nb*D_ + d0+row)*HW_ + p0+col];
  }
  __syncthreads();
  #pragma unroll
  for (int it=0; it<16; ++it) {
    int i = it*256 + tid; int row = i>>6, col = i&63;
    out[(size_t)((ni*HW_ + p0+row)*B_ + bi)*D_ + d0+col] = tile[col][row];
  }
}

// ---- 2: rel q projection + cnorm ----
__global__ void __launch_bounds__(256) k_qrel(float* ws, const float* WK) {
  int bx = blockIdx.x;
  int rg = bx & 127, which = bx >> 7;
  const float* Tr = ws + (which ? OFF_TTR : OFF_TSR);
  const float* Ti = ws + (which ? OFF_TTI : OFF_TSI);
  float* Qr = ws + (which ? OFF_QTR : OFF_QSR);
  float* Qi = ws + (which ? OFF_QTI : OFF_QSI);
  int R0 = rg*8;
  __shared__ float Xr[8][512], Xi[8][512];
  int tid = threadIdx.x;
  const float4* tr4 = (const float4*)(Tr + (size_t)R0*D_);
  const float4* ti4 = (const float4*)(Ti + (size_t)R0*D_);
  #pragma unroll
  for (int it=0; it<4; ++it) {
    int i = it*256 + tid;
    ((float4*)&Xr[0][0])[i] = tr4[i];
    ((float4*)&Xi[0][0])[i] = ti4[i];
  }
  __syncthreads();
  int row = tid >> 5, col2 = (tid & 31)*2;
  float a0r=0.f, a0i=0.f, a1r=0.f, a1i=0.f;
  #pragma unroll 4
  for (int d=0; d<512; ++d) {
    float2 w = *(const float2*)&WK[(size_t)d*DK_ + col2];
    float xr = Xr[row][d], xi = Xi[row][d];
    a0r += xr*w.x; a1r += xr*w.y;
    a0i += xi*w.x; a1i += xi*w.y;
  }
  float ss = wave_sum32(a0r*a0r + a1r*a1r + a0i*a0i + a1i*a1i);
  float inv = 1.f / sqrtf(ss + 1e-12f);
  size_t o = (size_t)(R0+row)*DK_ + col2;
  Qr[o]   = a0r*inv; Qr[o+1] = a1r*inv;
  Qi[o]   = a0i*inv; Qi[o+1] = a1i*inv;
}

// ---- 2b: gram scores into A ----
__global__ void __launch_bounds__(128) k_gram(float* ws) {
  int bx = blockIdx.x;
  int lt = bx & 3, qt = (bx>>2)&7, nb = (bx>>5)&3, which = bx>>7;
  int ni = nb>>1, bi = nb&1;
  const float* Qr = ws + (which ? OFF_QTR : OFF_QSR);
  const float* Qi = ws + (which ? OFF_QTI : OFF_QSI);
  float* A = ws + (which ? OFF_AT : OFF_AS) + (size_t)nb*65536;
  __shared__ float Qrs[32][33], Qis[32][33], Krs[32][68], Kis[32][68];
  int tid = threadIdx.x, ty = tid>>4, tx = tid&15;
  int ty4 = ty*4, tx4 = tx*4;
  float acc[4][4] = {};
  for (int c = 0; c < 2; ++c) {
    #pragma unroll
    for (int it = 0; it < 8; ++it) {
      int i = it*128 + tid; int row = i>>5, col = i&31;
      size_t qa = (size_t)((ni*HW_ + qt*32+row)*B_ + bi)*DK_ + c*32 + col;
      Qrs[row][col] = Qr[qa];
      Qis[row][col] = Qi[qa];
    }
    #pragma unroll
    for (int it = 0; it < 16; ++it) {
      int i = it*128 + tid; int kk = i&31, col = i>>5;
      size_t ka = (size_t)((ni*HW_ + lt*64+col)*B_ + bi)*DK_ + c*32 + kk;
      Krs[kk][col] = Qr[ka];
      Kis[kk][col] = Qi[ka];
    }
    __syncthreads();
    #pragma unroll
    for (int kk = 0; kk < 32; ++kk) {
      float4 kr = *(const float4*)&Krs[kk][tx4];
      float4 ki = *(const float4*)&Kis[kk][tx4];
      #pragma unroll
      for (int i = 0; i < 4; ++i) {
        float qr = Qrs[ty4+i][kk], qi = Qis[ty4+i][kk];
        acc[i][0] += qr*kr.x + qi*ki.x;
        acc[i][1] += qr*kr.y + qi*ki.y;
        acc[i][2] += qr*kr.z + qi*ki.z;
        acc[i][3] += qr*kr.w + qi*ki.w;
      }
    }
    __syncthreads();
  }
  #pragma unroll
  for (int i = 0; i < 4; ++i)
    #pragma unroll
    for (int j = 0; j < 4; ++j)
      A[(size_t)(qt*32+ty4+i)*256 + lt*64+tx4+j] = acc[i][j];
}

// ---- 3: rel self-attn. Wave-per-q-row; per-wave private 16KB LDS ring
// (8 slots x {er,ei} x 1KB) filled by global_load_lds, consumed via asm
// ds_read_b128 gated by counted s_waitcnt vmcnt(14) (never 0 in steady
// state). 16 x 1KB in flight per wave, ~128KB/CU. No barriers. ----
__global__ void __launch_bounds__(256, 2) k_selfattn(float* ws, const float* esr, const float* esi,
                                                     const float* etr, const float* eti) {
  __shared__ float ring[4][8][2][256];   // 64 KB; [wave][slot][tensor][1KB row]
  int idx = blockIdx.x;              // 512 = which(2)*nb(4)*iqt(64)
  int iqt = idx & 63, nb = (idx>>6)&3, which = idx>>8;
  int ni = nb>>1, bi = nb&1;
  const float* Qr = ws + (which ? OFF_QTR : OFF_QSR);
  const float* Qi = ws + (which ? OFF_QTI : OFF_QSI);
  const float* er = which ? etr : esr;
  const float* ei = which ? eti : esi;
  int tid = threadIdx.x, w = tid>>6, lane = tid&63;
  int iq = iqt*4 + w;                // one wave owns one q-row
  float* Arow = ws + (which ? OFF_AT : OFF_AS) + (size_t)nb*65536 + (size_t)iq*256;
  int tokq = ni*HW_ + iq;
  float qvr = Qr[(size_t)(tokq*B_ + bi)*DK_ + lane];   // lane = k
  float qvi = Qi[(size_t)(tokq*B_ + bi)*DK_ + lane];
  const float* gr = er + (size_t)nb*4194304 + (size_t)iq*256 + lane*4;  // + k*65536
  const float* gi = ei + (size_t)nb*4194304 + (size_t)iq*256 + lane*4;
  unsigned ldsb = (unsigned)(size_t)(__attribute__((address_space(3))) char*)&ring[w][0][0][0]
                + (unsigned)lane*16u;
  // prologue: fill 8 slots (k=0..7) -> 16 outstanding
  #pragma unroll
  for (int s = 0; s < 8; ++s) {
    gload16(gr + (size_t)s*65536, &ring[w][s][0][0]);
    gload16(gi + (size_t)s*65536, &ring[w][s][1][0]);
  }
  float a0=0.f, a1=0.f, a2=0.f, a3=0.f;
#define STEP(u, GSTR, KK, DOISS)                                              \
  { asm volatile("s_waitcnt vmcnt(" GSTR ")" ::: "memory");                   \
    __builtin_amdgcn_sched_barrier(0);                                        \
    f4 Rv, Iv;                                                                \
    asm volatile("ds_read_b128 %0, %2\n\tds_read_b128 %1, %2 offset:1024"     \
                 : "=v"(Rv), "=v"(Iv) : "v"(ldsb + (u)*2048u) : "memory");    \
    asm volatile("s_waitcnt lgkmcnt(0)" ::: "memory");                        \
    __builtin_amdgcn_sched_barrier(0);                                        \
    if (DOISS) {                                                              \
      gload16(gr + (size_t)((KK)+8)*65536, &ring[w][u][0][0]);                \
      gload16(gi + (size_t)((KK)+8)*65536, &ring[w][u][1][0]);                \
    }                                                                         \
    float fr = __shfl(qvr, (KK)), fi = __shfl(qvi, (KK));                     \
    a0 += fr*Rv[0] + fi*Iv[0];                                                \
    a1 += fr*Rv[1] + fi*Iv[1];                                                \
    a2 += fr*Rv[2] + fi*Iv[2];                                                \
    a3 += fr*Rv[3] + fi*Iv[3];                                                \
  }
  for (int kb = 0; kb < 56; kb += 8) {   // k = 0..55, each re-issues k+8
    STEP(0, "14", kb+0, true)
    STEP(1, "14", kb+1, true)
    STEP(2, "14", kb+2, true)
    STEP(3, "14", kb+3, true)
    STEP(4, "14", kb+4, true)
    STEP(5, "14", kb+5, true)
    STEP(6, "14", kb+6, true)
    STEP(7, "14", kb+7, true)
  }
  STEP(0, "14", 56, false)               // drain tail: gates (63-k)*2
  STEP(1, "12", 57, false)
  STEP(2, "10", 58, false)
  STEP(3, "8",  59, false)
  STEP(4, "6",  60, false)
  STEP(5, "4",  61, false)
  STEP(6, "2",  62, false)
  STEP(7, "0",  63, false)
#undef STEP
  int l0 = lane*4;
  float4 g = *(const float4*)&Arow[l0];  // gram seed
  float s0=(a0+g.x)*30.f, s1=(a1+g.y)*30.f, s2=(a2+g.z)*30.f, s3=(a3+g.w)*30.f;
  float m = wave_max64(fmaxf(fmaxf(s0,s1), fmaxf(s2,s3)));
  float e0=__expf(s0-m), e1=__expf(s1-m), e2=__expf(s2-m), e3=__expf(s3-m);
  float inv = 1.f / wave_sum64(e0+e1+e2+e3);
  *(float4*)&Arow[l0] = make_float4(e0*inv, e1*inv, e2*inv, e3*inv);
}

// ---- 4: Y = tok + A @ tok, fused P1 = ss(Y) per-block partial slots ----
__global__ void __launch_bounds__(128) k_selfapply(float* ws) {
  int bx = blockIdx.x;               // 512 = which(2)*nb(4)*qt(8)*dt(8)
  int dt = bx & 7, qt = (bx>>3)&7, nb = (bx>>6)&3, which = bx>>8;
  int ni = nb>>1, bi = nb&1;
  const float* A  = ws + (which ? OFF_AT : OFF_AS) + (size_t)nb*65536;
  const float* Xr = ws + (which ? OFF_TTR : OFF_TSR);
  const float* Xi = ws + (which ? OFF_TTI : OFF_TSI);
  float* Yr = ws + (which ? OFF_YTR : OFF_YSR);
  float* Yi = ws + (which ? OFF_YTI : OFF_YSI);
  __shared__ float As[32][33], Xrs[32][68], Xis[32][68];
  __shared__ float red[128];
  int tid = threadIdx.x, ty = tid>>4, tx = tid&15;
  int ty4 = ty*4, tx4 = tx*4;
  float ar[4][4] = {}, ai[4][4] = {};
  for (int c = 0; c < 8; ++c) {
    #pragma unroll
    for (int it = 0; it < 8; ++it) {
      int i = it*128 + tid; int row = i>>5, col = i&31;
      As[row][col] = A[(size_t)(qt*32+row)*256 + c*32+col];
    }
    #pragma unroll
    for (int it = 0; it < 16; ++it) {
      int i = it*128 + tid; int row = i>>6, col = i&63;
      size_t xb = (size_t)((ni*HW_ + c*32+row)*B_ + bi)*D_ + dt*64+col;
      Xrs[row][col] = Xr[xb]; Xis[row][col] = Xi[xb];
    }
    __syncthreads();
    #pragma unroll
    for (int kk = 0; kk < 32; ++kk) {
      float4 vr = *(const float4*)&Xrs[kk][tx4];
      float4 vi = *(const float4*)&Xis[kk][tx4];
      #pragma unroll
      for (int i = 0; i < 4; ++i) {
        float a = As[ty4+i][kk];
        ar[i][0] += a*vr.x; ar[i][1] += a*vr.y; ar[i][2] += a*vr.z; ar[i][3] += a*vr.w;
        ai[i][0] += a*vi.x; ai[i][1] += a*vi.y; ai[i][2] += a*vi.z; ai[i][3] += a*vi.w;
      }
    }
    __syncthreads();
  }
  float ssr = 0.f, ssi = 0.f;
  #pragma unroll
  for (int i = 0; i < 4; ++i) {
    size_t o = (size_t)((ni*HW_ + qt*32 + ty4+i)*B_ + bi)*D_ + dt*64 + tx4;
    #pragma unroll
    for (int j = 0; j < 4; ++j) {
      float yr = Xr[o+j] + ar[i][j];
      float yi = Xi[o+j] + ai[i][j];
      Yr[o+j] = yr; Yi[o+j] = yi;
      ssr += yr*yr; ssi += yi*yi;
    }
  }
  float tr_ = blk_sum<128>(ssr, red);
  float ti_ = blk_sum<128>(ssi, red);
  if (tid == 0) {
    ws[OFF_P1 + (size_t)((which*2+0)*G_ + nb)*64 + qt*8 + dt] = tr_;
    ws[OFF_P1 + (size_t)((which*2+1)*G_ + nb)*64 + qt*8 + dt] = ti_;
  }
}

// ---- 8: cross q/k projection + cnorm (scales folded in) ----
__global__ void __launch_bounds__(256) k_crossproj(float* ws, const float* W) {
  int bx = blockIdx.x;
  int rg = bx & 127, isK = bx >> 7;
  const float* inR = ws + (isK ? OFF_YSR : OFF_YTR);
  const float* inI = ws + (isK ? OFF_YSI : OFF_YTI);
  float* oR = ws + (isK ? OFF_KCR : OFF_QCR);
  float* oI = ws + (isK ? OFF_KCI : OFF_QCI);
  int R0 = rg*8;
  __shared__ float Xr[8][512], Xi[8][512];
  int tid = threadIdx.x;
  const float4* xr4 = (const float4*)(inR + (size_t)R0*D_);
  const float4* xi4 = (const float4*)(inI + (size_t)R0*D_);
  #pragma unroll
  for (int it=0; it<4; ++it) {
    int i = it*256 + tid;
    ((float4*)&Xr[0][0])[i] = xr4[i];
    ((float4*)&Xi[0][0])[i] = xi4[i];
  }
  __syncthreads();
  int row = tid >> 5, col4 = (tid & 31)*4;
  float ar[4]={}, ai[4]={};
  #pragma unroll 4
  for (int d=0; d<512; ++d) {
    float4 w = *(const float4*)&W[(size_t)d*DKC_ + col4];
    float xr = Xr[row][d], xi = Xi[row][d];
    ar[0] += xr*w.x; ar[1] += xr*w.y; ar[2] += xr*w.z; ar[3] += xr*w.w;
    ai[0] += xi*w.x; ai[1] += xi*w.y; ai[2] += xi*w.z; ai[3] += xi*w.w;
  }
  int rr = R0 + row;
  int bi = rr & 1, gg = ((rr>>1)>>8)*2 + bi;
  float sR = scale_from64(ws + OFF_P1, (isK?0:2)*G_ + gg);
  float sI = scale_from64(ws + OFF_P1, (isK?1:3)*G_ + gg);
  ar[0]*=sR; ar[1]*=sR; ar[2]*=sR; ar[3]*=sR;
  ai[0]*=sI; ai[1]*=sI; ai[2]*=sI; ai[3]*=sI;
  float ps = ar[0]*ar[0]+ar[1]*ar[1]+ar[2]*ar[2]+ar[3]*ar[3]
           + ai[0]*ai[0]+ai[1]*ai[1]+ai[2]*ai[2]+ai[3]*ai[3];
  float ss = wave_sum32(ps);
  float inv = 1.f / sqrtf(ss + 1e-12f);
  size_t o = (size_t)rr*DKC_ + col4;
  oR[o]   = ar[0]*inv; oR[o+1] = ar[1]*inv; oR[o+2] = ar[2]*inv; oR[o+3] = ar[3]*inv;
  oI[o]   = ai[0]*inv; oI[o+1] = ai[1]*inv; oI[o+2] = ai[2]*inv; oI[o+3] = ai[3]*inv;
}

// ---- 9: raw cross scores ----
__global__ void __launch_bounds__(128) k_crossscore(float* ws) {
  int bx = blockIdx.x;
  int lt = bx & 7, qt = (bx>>3)&15, bi = bx>>7;
  const float* Qr = ws + OFF_QCR; const float* Qi = ws + OFF_QCI;
  const float* Kr = ws + OFF_KCR; const float* Ki = ws + OFF_KCI;
  float* S = ws + OFF_AC + (size_t)bi*262144;
  __shared__ float Qrs[32][33], Qis[32][33], Krs[32][68], Kis[32][68];
  int tid = threadIdx.x, ty = tid>>4, tx = tid&15;
  int ty4 = ty*4, tx4 = tx*4;
  float acc[4][4] = {};
  for (int c = 0; c < 4; ++c) {
    #pragma unroll
    for (int it = 0; it < 8; ++it) {
      int i = it*128 + tid; int row = i>>5, col = i&31;
      Qrs[row][col] = Qr[(size_t)((qt*32+row)*B_ + bi)*DKC_ + c*32 + col];
      Qis[row][col] = Qi[(size_t)((qt*32+row)*B_ + bi)*DKC_ + c*32 + col];
    }
    #pragma unroll
    for (int it = 0; it < 16; ++it) {
      int i = it*128 + tid; int kk = i&31, col = i>>5;
      Krs[kk][col] = Kr[(size_t)((lt*64+col)*B_ + bi)*DKC_ + c*32 + kk];
      Kis[kk][col] = Ki[(size_t)((lt*64+col)*B_ + bi)*DKC_ + c*32 + kk];
    }
    __syncthreads();
    #pragma unroll
    for (int kk = 0; kk < 32; ++kk) {
      float4 kr = *(const float4*)&Krs[kk][tx4];
      float4 ki = *(const float4*)&Kis[kk][tx4];
      #pragma unroll
      for (int i = 0; i < 4; ++i) {
        float qr = Qrs[ty4+i][kk], qi = Qis[ty4+i][kk];
        acc[i][0] += qr*kr.x + qi*ki.x;
        acc[i][1] += qr*kr.y + qi*ki.y;
        acc[i][2] += qr*kr.z + qi*ki.z;
        acc[i][3] += qr*kr.w + qi*ki.w;
      }
    }
    __syncthreads();
  }
  #pragma unroll
  for (int i = 0; i < 4; ++i)
    #pragma unroll
    for (int j = 0; j < 4; ++j)
      S[(size_t)(qt*32+ty4+i)*512 + lt*64+tx4+j] = acc[i][j];
}

// ---- 10: softmax per row + mask scalars ----
__global__ void k_softmaxrow(float* ws, const float* posr, const float* posi) {
  int bx = blockIdx.x;
  int bi = bx >> 9, iq = bx & 511;
  float* row = ws + OFF_AC + (size_t)bi*262144 + (size_t)iq*512;
  int tid = threadIdx.x;
  float s0 = row[tid]*30.f, s1 = row[tid+256]*30.f;
  __shared__ float sh[256];
  float m = blk_max<256>(fmaxf(s0, s1), sh);
  float e0 = __expf(s0 - m), e1 = __expf(s1 - m);
  float sum = blk_sum<256>(e0 + e1, sh);
  float inv = 1.f / sum;
  float a0 = e0*inv, a1 = e1*inv;
  row[tid] = a0; row[tid+256] = a1;
  float pr0 = posr[bi*HW_ + tid],        pr1 = posr[(B_+bi)*HW_ + tid];
  float pi0 = posi[bi*HW_ + tid],        pi1 = posi[(B_+bi)*HW_ + tid];
  float mr = blk_sum<256>(a0*pr0 + a1*pr1, sh);
  float mi = blk_sum<256>(a0*pi0 + a1*pi1, sh);
  if (!tid) { ws[OFF_MR + bi*512 + iq] = mr; ws[OFF_MI + bi*512 + iq] = mi; }
}

// ---- 11: t3 = A @ (s_mem*mem * pos), split-K=2 ----
__global__ void __launch_bounds__(128) k_crossapply(float* ws, const float* posr, const float* posi) {
  int bx = blockIdx.x;
  int dt = bx & 7, qt = (bx>>3)&15, bi = (bx>>7)&1, kc = bx>>8;
  const float* A  = ws + OFF_AC + (size_t)bi*262144;
  const float* Mr = ws + OFF_YSR; const float* Mi = ws + OFF_YSI;
  float* Pr = ws + (kc ? OFF_TSR : OFF_T3R);
  float* Pi = ws + (kc ? OFF_TSI : OFF_T3I);
  float smr = scale_from64(ws + OFF_P1, 0*G_ + kc*2 + bi);
  float smi = scale_from64(ws + OFF_P1, 1*G_ + kc*2 + bi);
  __shared__ float As[32][33], Vrs[32][68], Vis[32][68];
  int tid = threadIdx.x, ty = tid>>4, tx = tid&15;
  int ty4 = ty*4, tx4 = tx*4;
  float ar[4][4] = {}, ai[4][4] = {};
  for (int c = 0; c < 8; ++c) {
    int kb = kc*256 + c*32;
    #pragma unroll
    for (int it = 0; it < 8; ++it) {
      int i = it*128 + tid; int row = i>>5, col = i&31;
      As[row][col] = A[(size_t)(qt*32+row)*512 + kb+col];
    }
    #pragma unroll
    for (int it = 0; it < 16; ++it) {
      int i = it*128 + tid; int row = i>>6, col = i&63;
      int l = kb + row; int pl = l & 255;
      float pvr = posr[(kc*B_ + bi)*HW_ + pl] * smr;
      float pvi = posi[(kc*B_ + bi)*HW_ + pl] * smi;
      size_t vb = (size_t)(l*B_ + bi)*D_ + dt*64+col;
      Vrs[row][col] = Mr[vb] * pvr;
      Vis[row][col] = Mi[vb] * pvi;
    }
    __syncthreads();
    #pragma unroll
    for (int kk = 0; kk < 32; ++kk) {
      float4 vr = *(const float4*)&Vrs[kk][tx4];
      float4 vi = *(const float4*)&Vis[kk][tx4];
      #pragma unroll
      for (int i = 0; i < 4; ++i) {
        float a = As[ty4+i][kk];
        ar[i][0] += a*vr.x; ar[i][1] += a*vr.y; ar[i][2] += a*vr.z; ar[i][3] += a*vr.w;
        ai[i][0] += a*vi.x; ai[i][1] += a*vi.y; ai[i][2] += a*vi.z; ai[i][3] += a*vi.w;
      }
    }
    __syncthreads();
  }
  #pragma unroll
  for (int i = 0; i < 4; ++i) {
    size_t o = (size_t)((qt*32+ty4+i)*B_ + bi)*D_ + dt*64 + tx4;
    #pragma unroll
    for (int j = 0; j < 4; ++j) { Pr[o+j] = ar[i][j]; Pi[o+j] = ai[i][j]; }
  }
}

// ---- 12: P2 partials ----
__global__ void k_reducey24(float* ws) {
  int qy = blockIdx.y;
  int g = blockIdx.x / NBLK_, blk = blockIdx.x % NBLK_;
  int ni = g>>1, bi = g&1;
  const float* X   = ws + ((qy==0 || qy==2) ? OFF_YTR : OFF_YTI);
  const float* T3a = ws + ((qy==2) ? OFF_T3R : OFF_T3I);
  const float* T3b = ws + ((qy==2) ? OFF_TSR : OFF_TSI);
  const float* M   = ws + ((qy==0) ? OFF_MR : OFF_MI);
  float sx = scale_from64(ws + OFF_P1, ((qy==0||qy==2) ? 2 : 3)*G_ + g);
  int tid = threadIdx.x;
  float acc = 0.f;
  for (int p = blk; p < HW_; p += NBLK_) {
    int l = ni*HW_ + p;
    size_t rb = (size_t)(l*B_ + bi)*D_;
    if (qy < 2) {
      float m = M[bi*512 + l] * sx;
      for (int d = tid; d < D_; d += 256) { float v = X[rb+d]*m; acc += v*v; }
    } else {
      for (int d = tid; d < D_; d += 256) { float v = X[rb+d]*sx + T3a[rb+d] + T3b[rb+d]; acc += v*v; }
    }
  }
  __shared__ float sh[256];
  float s = blk_sum<256>(acc, sh);
  if (!tid) ws[OFF_P2 + (size_t)(qy*G_ + g)*NBLK_ + blk] = s;
}

// ---- 14: z combine + P3 ----
__global__ void k_combine(float* ws) {
  int y = blockIdx.y;
  int g = blockIdx.x / NBLK_, blk = blockIdx.x % NBLK_;
  int ni = g>>1, bi = g&1;
  const float* X   = ws + (y ? OFF_YTI : OFF_YTR);
  float* T3a       = ws + (y ? OFF_T3I : OFF_T3R);
  const float* T3b = ws + (y ? OFF_TSI : OFF_TSR);
  const float* M   = ws + (y ? OFF_MI : OFF_MR);
  float sx = scale_from64(ws + OFF_P1, (2+y)*G_ + g);
  float a2 = scale_from(ws + OFF_P2, y*G_ + g);
  float a4 = scale_from(ws + OFF_P2, (2+y)*G_ + g);
  int tid = threadIdx.x;
  float acc = 0.f;
  for (int p = blk; p < HW_; p += NBLK_) {
    int l = ni*HW_ + p;
    float m = M[bi*512 + l];
    size_t rb = (size_t)(l*B_ + bi)*D_;
    for (int d = tid; d < D_; d += 256) {
      float x = X[rb+d] * sx;
      float z = a2*(x*m) + a4*(x + T3a[rb+d] + T3b[rb+d]);
      T3a[rb+d] = z;
      acc += z*z;
    }
  }
  __shared__ float sh[256];
  float s = blk_sum<256>(acc, sh);
  if (!tid) ws[OFF_P3 + (size_t)(y*G_ + g)*NBLK_ + blk] = s;
}

// ---- 16: out = z*scale; feat = transpose(out) ----
__global__ void k_final(float* ws, float* out) {
  int y = blockIdx.y;
  int bx = blockIdx.x;
  int pt = bx & 3, dt = (bx>>2)&7, nb = bx>>5;
  int ni = nb>>1, bi = nb&1;
  const float* Z = ws + (y ? OFF_T3I : OFF_T3R);
  float s = scale_from(ws + OFF_P3, y*G_ + nb);
  float* o1 = out + (size_t)y*524288;
  float* o2 = out + (size_t)(2+y)*524288;
  __shared__ float tile[64][65];
  int tid = threadIdx.x;
  int p0 = pt*64, d0 = dt*64;
  #pragma unroll
  for (int it = 0; it < 16; ++it) {
    int i = it*256 + tid; int row = i>>6, col = i&63;
    size_t idx = (size_t)((ni*HW_ + p0+row)*B_ + bi)*D_ + d0+col;
    float v = Z[idx] * s;
    o1[idx] = v;
    tile[row][col] = v;
  }
  __syncthreads();
  #pragma unroll
  for (int it = 0; it < 16; ++it) {
    int i = it*256 + tid; int row = i>>6, col = i&63;
    o2[(size_t)(nb*D_ + d0+row)*HW_ + p0+col] = tile[col][row];
  }
}

extern "C" void kernel_launch(void* const* d_in, const int* in_sizes, int n_in,
                              void* d_out, int out_size, void* d_ws, size_t ws_size,
                              hipStream_t stream) {
  const float* srcR = (const float*)d_in[0];
  const float* srcI = (const float*)d_in[1];
  const float* tgtR = (const float*)d_in[2];
  const float* tgtI = (const float*)d_in[3];
  const float* esr  = (const float*)d_in[4];
  const float* esi  = (const float*)d_in[5];
  const float* etr  = (const float*)d_in[6];
  const float* eti  = (const float*)d_in[7];
  const float* posR = (const float*)d_in[8];
  const float* posI = (const float*)d_in[9];
  const float* WKrel   = (const float*)d_in[10];
  const float* WKcross = (const float*)d_in[11];
  float* ws  = (float*)d_ws;
  float* out = (float*)d_out;

  k_transpose <<<dim3(128,4), 256, 0, stream>>>(srcR, srcI, tgtR, tgtI, ws);
  k_qrel      <<<256, 256, 0, stream>>>(ws, WKrel);
  k_gram      <<<256, 128, 0, stream>>>(ws);
  k_selfattn  <<<512, 256, 0, stream>>>(ws, esr, esi, etr, eti);
  k_selfapply <<<512, 128, 0, stream>>>(ws);
  k_crossproj <<<256, 256, 0, stream>>>(ws, WKcross);
  k_crossscore<<<256, 128, 0, stream>>>(ws);
  k_softmaxrow<<<1024, 256, 0, stream>>>(ws, posR, posI);
  k_crossapply<<<512, 128, 0, stream>>>(ws, posR, posI);
  k_reducey24 <<<dim3(G_*NBLK_,4), 256, 0, stream>>>(ws);
  k_combine   <<<dim3(G_*NBLK_,2), 256, 0, stream>>>(ws);
  k_final     <<<dim3(128,2), 256, 0, stream>>>(ws, out);
}